// Round 1
// baseline (47.371 us; speedup 1.0000x reference)
//
#include <hip/hip_runtime.h>

// RoPE with position gather.
// x:    [B=4, H=16, S=2048, D=128] f32
// rope: [4096, 128, 128] f32 (we only read the 2x2 rotation diagonals)
// tp:   [2048] int32 token positions
// out[b,h,s,:] = rotate(x[b,h,p,:], angles(p)),  p = tp[s]
//
// cos(p,i) = rope[p*16384 + 258*i], sin(p,i) = rope[p*16384 + 258*i + 1]
// (rope[s,2i,2i]=cos, rope[s,2i,2i+1]=sin -> adjacent floats, float2-aligned:
//  byte offset 1032*i within a 64KiB-aligned row.)

#define SEQL 2048
#define DK   128

__global__ void rope_gather_kernel(const float* __restrict__ x,
                                   const float* __restrict__ rope,
                                   const int* __restrict__ tp,
                                   float* __restrict__ out,
                                   int total_quads) {
    int idx    = blockIdx.x * blockDim.x + threadIdx.x;
    int stride = gridDim.x * blockDim.x;
    for (; idx < total_quads; idx += stride) {
        int row = idx >> 5;          // 32 float4-quads per 128-elem row
        int q   = idx & 31;          // quad index: elems [4q, 4q+3] = pairs 2q, 2q+1
        int s   = row & (SEQL - 1);  // seq index within (b,h)
        int bh  = row >> 11;         // combined batch*head
        int p   = tp[s];             // gathered position

        size_t xoff = ((size_t)bh * SEQL + (size_t)p) * DK + (q << 2);
        float4 xv = *reinterpret_cast<const float4*>(x + xoff);

        size_t roff = (size_t)p * (DK * DK);
        int i0 = q << 1;
        float2 cs0 = *reinterpret_cast<const float2*>(rope + roff + (size_t)258 * i0);
        float2 cs1 = *reinterpret_cast<const float2*>(rope + roff + (size_t)258 * (i0 + 1));

        float4 o;
        o.x = xv.x * cs0.x - xv.y * cs0.y;
        o.y = xv.x * cs0.y + xv.y * cs0.x;
        o.z = xv.z * cs1.x - xv.w * cs1.y;
        o.w = xv.z * cs1.y + xv.w * cs1.x;

        *reinterpret_cast<float4*>(out + (size_t)row * DK + (q << 2)) = o;
    }
}

extern "C" void kernel_launch(void* const* d_in, const int* in_sizes, int n_in,
                              void* d_out, int out_size, void* d_ws, size_t ws_size,
                              hipStream_t stream) {
    const float* x    = (const float*)d_in[0];
    const float* rope = (const float*)d_in[1];
    const int*   tp   = (const int*)d_in[2];
    float*       out  = (float*)d_out;

    // total quads = B*H*S*(D/4) = 4*16*2048*32
    const int total_quads = 4 * 16 * SEQL * (DK / 4);
    const int block = 256;
    const int grid  = 4096;  // grid-stride, 4 iterations/thread
    rope_gather_kernel<<<grid, block, 0, stream>>>(x, rope, tp, out, total_quads);
}

// Round 2
// 30.325 us; speedup vs baseline: 1.5621x; 1.5621x over previous
//
#include <hip/hip_runtime.h>

// RoPE with position gather — block-per-s formulation.
// x:    [B=4, H=16, S=2048, D=128] f32
// rope: [4096, 128, 128] f32 (only the 2x2 rotation diagonals are read)
// tp:   [2048] int32 token positions
// out[b,h,s,:] = rotate(x[b,h,p,:], angles(p)),  p = tp[s]
//
// cos(p,i) = rope[p*16384 + 258*i], sin(p,i) = rope[p*16384 + 258*i + 1]
//
// Grid: one block per s (2048 blocks, 256 threads).
// Thread (q = tid&31, g = tid>>5): loads its cos/sin pair ONCE (the scattered
// stride-1032B read), then streams 8 coalesced float4 rows across bh = g,
// g+8, ..., g+56. Rope request traffic: 64 threads-worth per block instead of
// per row-visit (64x reduction vs the flat grid-stride version).

#define SEQL 2048
#define DK   128
#define NBH  64            // B*H = 4*16

__global__ __launch_bounds__(256) void rope_gather_kernel(
        const float* __restrict__ x,
        const float* __restrict__ rope,
        const int* __restrict__ tp,
        float* __restrict__ out) {
    const int s = blockIdx.x;
    const int p = tp[s];               // wave-uniform scalar load
    const int q = threadIdx.x & 31;    // float4-quad within the 128-elem row
    const int g = threadIdx.x >> 5;    // bh group 0..7

    const float* rp = rope + (size_t)p * (DK * DK);
    const int i0 = q << 1;
    const float2 cs0 = *reinterpret_cast<const float2*>(rp + (size_t)258 * i0);
    const float2 cs1 = *reinterpret_cast<const float2*>(rp + (size_t)258 * (i0 + 1));

    const size_t rowstride = (size_t)SEQL * DK;           // stride between bh slices
    const size_t xbase = (size_t)p * DK + (q << 2);
    const size_t obase = (size_t)s * DK + (q << 2);

    #pragma unroll
    for (int bh = g; bh < NBH; bh += 8) {
        const float4 xv = *reinterpret_cast<const float4*>(x + xbase + (size_t)bh * rowstride);
        float4 o;
        o.x = xv.x * cs0.x - xv.y * cs0.y;
        o.y = xv.x * cs0.y + xv.y * cs0.x;
        o.z = xv.z * cs1.x - xv.w * cs1.y;
        o.w = xv.z * cs1.y + xv.w * cs1.x;
        *reinterpret_cast<float4*>(out + obase + (size_t)bh * rowstride) = o;
    }
}

extern "C" void kernel_launch(void* const* d_in, const int* in_sizes, int n_in,
                              void* d_out, int out_size, void* d_ws, size_t ws_size,
                              hipStream_t stream) {
    const float* x    = (const float*)d_in[0];
    const float* rope = (const float*)d_in[1];
    const int*   tp   = (const int*)d_in[2];
    float*       out  = (float*)d_out;

    rope_gather_kernel<<<SEQL, 256, 0, stream>>>(x, rope, tp, out);
}